// Round 2
// baseline (3443.916 us; speedup 1.0000x reference)
//
#include <hip/hip_runtime.h>
#include <stdint.h>

#define N_NODES 100000
#define N_EDGES 3200000
#define IN_DIM 128
#define HID 64
#define N_GRAPHS 64
#define BN_EPS 1e-5f
#define NSHARD 16
#define BUCK_SH 7
#define BUCK_SZ 128
#define NBUCK ((N_NODES + BUCK_SZ - 1) / BUCK_SZ)   // 782
#define NCNT (NBUCK * 8)                             // 6256
#define BIN_GRID 2048

// ---------------------------------------------------------------------------
// count edges per (bucket, sub-stream). s=(e>>8)&7 is deterministic and
// matches the default blockIdx->XCD round-robin for 256-thread blocks.
__global__ void k_count(const int* __restrict__ ei, int* __restrict__ cnt2) {
    int stride = gridDim.x * blockDim.x;
    for (int e = blockIdx.x * blockDim.x + threadIdx.x; e < N_EDGES; e += stride) {
        int c = ei[N_EDGES + e];
        int s = (e >> 8) & 7;
        atomicAdd(&cnt2[((c >> BUCK_SH) << 3) + s], 1);
    }
}

// single-block exclusive scan of cnt2[6256] -> soff[6257]; also init cursors
__global__ void k_scan6k(const int* __restrict__ cnt2, int* __restrict__ soff,
                         int* __restrict__ cur) {
    __shared__ int parts[256];
    int t = threadIdx.x;
    int s = 0;
    for (int i = 0; i < 25; ++i) {
        int idx = t * 25 + i;
        if (idx < NCNT) s += cnt2[idx];
    }
    parts[t] = s;
    __syncthreads();
    for (int off = 1; off < 256; off <<= 1) {
        int x = (t >= off) ? parts[t - off] : 0;
        __syncthreads();
        parts[t] += x;
        __syncthreads();
    }
    int run = (t > 0) ? parts[t - 1] : 0;
    for (int i = 0; i < 25; ++i) {
        int idx = t * 25 + i;
        if (idx < NCNT) {
            soff[idx] = run;
            cur[idx] = run;
            run += cnt2[idx];
        }
    }
    if (t == 255) soff[NCNT] = parts[255];
}

// bin edges: ebuf[p] = {r | (c_local<<17), w}
__global__ void k_bin(const int* __restrict__ ei, const float* __restrict__ ew,
                      int* __restrict__ cur, uint2* __restrict__ ebuf) {
    int stride = gridDim.x * blockDim.x;
    for (int e = blockIdx.x * blockDim.x + threadIdx.x; e < N_EDGES; e += stride) {
        int r = ei[e];
        int c = ei[N_EDGES + e];
        float w = ew[e];
        int s = (e >> 8) & 7;
        int p = atomicAdd(&cur[((c >> BUCK_SH) << 3) + s], 1);
        ebuf[p] = make_uint2((unsigned)(r | ((c & (BUCK_SZ - 1)) << 17)),
                             __float_as_uint(w));
    }
}

// per-bucket degree -> dinv (all edges with col c live in c's bucket)
__global__ __launch_bounds__(256) void k_degb(const uint2* __restrict__ ebuf,
                                              const int* __restrict__ soff,
                                              float* __restrict__ dinv) {
    __shared__ float dacc[BUCK_SZ];
    int b = blockIdx.x, t = threadIdx.x;
    if (t < BUCK_SZ) dacc[t] = 0.f;
    __syncthreads();
    int beg = soff[b << 3], end = soff[(b << 3) + 8];
    for (int i = beg + t; i < end; i += 256) {
        uint2 u = ebuf[i];
        atomicAdd(&dacc[u.x >> 17], __uint_as_float(u.y));
    }
    __syncthreads();
    int node = b * BUCK_SZ + t;
    if (t < BUCK_SZ && node < N_NODES) dinv[node] = rsqrtf(dacc[t] + 1.0f);
}

// norm = dinv[r]*w*dinv[c], overwriting w in ebuf (rewritten fresh every call)
__global__ __launch_bounds__(256) void k_norm(uint2* __restrict__ ebuf,
                                              const int* __restrict__ soff,
                                              const float* __restrict__ dinv) {
    __shared__ float sdi[BUCK_SZ];
    int b = blockIdx.x, t = threadIdx.x;
    if (t < BUCK_SZ) {
        int node = b * BUCK_SZ + t;
        sdi[t] = (node < N_NODES) ? dinv[node] : 0.f;
    }
    __syncthreads();
    int beg = soff[b << 3], end = soff[(b << 3) + 8];
    for (int i = beg + t; i < end; i += 256) {
        uint2 u = ebuf[i];
        int r = u.x & 131071;
        int cl = u.x >> 17;
        float nm = dinv[r] * __uint_as_float(u.y) * sdi[cl];
        ebuf[i].y = __float_as_uint(nm);
    }
}

// ---------------------------------------------------------------------------
// GEMM: out[n][c] = sum_k in[n][k] * W[k][c], optional fused BN+ReLU on input
template <int K, bool BN>
__global__ __launch_bounds__(256) void k_gemm(const float* __restrict__ in,
                                              const float* __restrict__ W,
                                              const float* __restrict__ scale,
                                              const float* __restrict__ shift,
                                              float* __restrict__ out) {
    __shared__ float ws[K * 64];
    __shared__ float xs[32 * 132];
    __shared__ float ssc[64], ssh[64];
    int t = threadIdx.x;
    int nbase = blockIdx.x * 128;

#pragma unroll
    for (int i = 0; i < K / 16; ++i) {
        int idx = t + 256 * i;
        ((float4*)ws)[idx] = ((const float4*)W)[idx];
    }
    if (BN && t < 64) { ssc[t] = scale[t]; ssh[t] = shift[t]; }

    int cg = t & 15;
    int ng = t >> 4;
    float acc[8][4];
#pragma unroll
    for (int i = 0; i < 8; ++i)
#pragma unroll
        for (int j = 0; j < 4; ++j) acc[i][j] = 0.f;

    for (int k0 = 0; k0 < K; k0 += 32) {
        __syncthreads();
#pragma unroll
        for (int i = 0; i < 4; ++i) {
            int idx = t + 256 * i;
            int row = idx >> 3;
            int kq = idx & 7;
            int node = nbase + row;
            float4 v = make_float4(0.f, 0.f, 0.f, 0.f);
            if (node < N_NODES)
                v = *(const float4*)(in + (size_t)node * K + k0 + kq * 4);
            float vv[4] = {v.x, v.y, v.z, v.w};
#pragma unroll
            for (int u = 0; u < 4; ++u) {
                float val = vv[u];
                if (BN) {
                    int k = k0 + kq * 4 + u;
                    val = fmaxf(ssc[k] * val + ssh[k], 0.f);
                }
                xs[(kq * 4 + u) * 132 + row] = val;
            }
        }
        __syncthreads();
#pragma unroll
        for (int k = 0; k < 32; ++k) {
            float4 wv = *(const float4*)(ws + (k0 + k) * 64 + cg * 4);
            float4 xa = *(const float4*)(xs + k * 132 + ng * 8);
            float4 xb = *(const float4*)(xs + k * 132 + ng * 8 + 4);
            float xv[8] = {xa.x, xa.y, xa.z, xa.w, xb.x, xb.y, xb.z, xb.w};
            float wvv[4] = {wv.x, wv.y, wv.z, wv.w};
#pragma unroll
            for (int i = 0; i < 8; ++i)
#pragma unroll
                for (int j = 0; j < 4; ++j) acc[i][j] += xv[i] * wvv[j];
        }
    }
#pragma unroll
    for (int i = 0; i < 8; ++i) {
        int node = nbase + ng * 8 + i;
        if (node < N_NODES) {
            float4 o4 = make_float4(acc[i][0], acc[i][1], acc[i][2], acc[i][3]);
            *(float4*)(out + (size_t)node * 64 + cg * 4) = o4;
        }
    }
}

// ---------------------------------------------------------------------------
// bucket aggregation with LDS accumulator [128 dests x 64 ch] + fused BN stats
__global__ __launch_bounds__(512) void k_agg(const float* __restrict__ hin,
                                             const uint2* __restrict__ ebuf,
                                             const int* __restrict__ soff,
                                             const float* __restrict__ dinv,
                                             const float* __restrict__ bias,
                                             float* __restrict__ hout,
                                             float* __restrict__ bn_shard) {
    __shared__ float acc[BUCK_SZ * 64];
    __shared__ float sred[2 * 8 * 64];
    int b = blockIdx.x, t = threadIdx.x;
    int wid = t >> 6, lane = t & 63;
#pragma unroll
    for (int i = 0; i < BUCK_SZ * 64 / 512; ++i) acc[t + i * 512] = 0.f;
    __syncthreads();

    int beg = soff[b << 3], end = soff[(b << 3) + 8];
    for (int j0 = beg + wid * 64; j0 < end; j0 += 512) {
        int nv = min(64, end - j0);
        uint2 u = (j0 + lane < end) ? ebuf[j0 + lane] : make_uint2(0u, 0u);
        int pk = (int)u.x;
        float nm = __uint_as_float(u.y);
#pragma unroll 4
        for (int jj = 0; jj < nv; ++jj) {
            int p = __shfl(pk, jj);
            float nmj = __shfl(nm, jj);
            int r = p & 131071;
            int cl = p >> 17;
            atomicAdd(&acc[(cl << 6) + lane], nmj * hin[((size_t)r << 6) + lane]);
        }
    }
    __syncthreads();

    // epilogue: self-loop + bias, write out, BN partial sums
    float s = 0.f, q = 0.f;
    float bl = bias[lane];
    for (int cl = wid; cl < BUCK_SZ; cl += 8) {
        int node = b * BUCK_SZ + cl;
        if (node < N_NODES) {
            float dv = dinv[node];
            float val = acc[(cl << 6) + lane] + dv * dv * hin[((size_t)node << 6) + lane] + bl;
            hout[((size_t)node << 6) + lane] = val;
            s += val;
            q += val * val;
        }
    }
    sred[wid * 64 + lane] = s;
    sred[512 + wid * 64 + lane] = q;
    __syncthreads();
    if (wid == 0) {
        float ts = 0.f, tq = 0.f;
#pragma unroll
        for (int i = 0; i < 8; ++i) {
            ts += sred[i * 64 + lane];
            tq += sred[512 + i * 64 + lane];
        }
        float* shard = bn_shard + (b & (NSHARD - 1)) * 128;
        atomicAdd(&shard[lane], ts);
        atomicAdd(&shard[64 + lane], tq);
    }
}

// reduce BN shards -> scale/shift; re-zero shards for the next layer
__global__ void k_bn_final(float* __restrict__ bn_shard, const float* __restrict__ gamma,
                           const float* __restrict__ beta, float* __restrict__ scale,
                           float* __restrict__ shift) {
    int t = threadIdx.x;
    if (t < 64) {
        float s = 0.f, q = 0.f;
        for (int i = 0; i < NSHARD; ++i) {
            s += bn_shard[i * 128 + t];
            q += bn_shard[i * 128 + 64 + t];
        }
        float mean = s * (1.0f / N_NODES);
        float var = q * (1.0f / N_NODES) - mean * mean;
        float sc = gamma[t] * rsqrtf(var + BN_EPS);
        scale[t] = sc;
        shift[t] = beta[t] - mean * sc;
    }
    __syncthreads();
    for (int i = t; i < NSHARD * 128; i += 256) bn_shard[i] = 0.f;
}

// ---------------------------------------------------------------------------
__global__ __launch_bounds__(256) void k_pool(const float* __restrict__ a2,
                                              const float* __restrict__ scale,
                                              const float* __restrict__ shift,
                                              const int* __restrict__ batch,
                                              float* __restrict__ pooled,
                                              float* __restrict__ pcnt) {
    int t = threadIdx.x;
    int c = t & 63;
    int rg = t >> 6;
    int base = blockIdx.x * 1024;
    float sc = scale[c], sh = shift[c];
    int gcur = -1;
    float acc = 0.f, cacc = 0.f;
    for (int i = rg; i < 1024; i += 4) {
        int v = base + i;
        if (v >= N_NODES) break;
        int g = batch[v];
        if (g != gcur) {
            if (gcur >= 0) {
                atomicAdd(&pooled[gcur * 64 + c], acc);
                if (c == 0) atomicAdd(&pcnt[gcur], cacc);
            }
            gcur = g;
            acc = 0.f;
            cacc = 0.f;
        }
        float h = fmaxf(sc * a2[(size_t)v * 64 + c] + sh, 0.f);
        acc += h;
        cacc += 1.f;
    }
    if (gcur >= 0) {
        atomicAdd(&pooled[gcur * 64 + c], acc);
        if (c == 0) atomicAdd(&pcnt[gcur], cacc);
    }
}

__global__ void k_out(const float* __restrict__ pooled, const float* __restrict__ pcnt,
                      const float* __restrict__ Wout, const float* __restrict__ bout,
                      float* __restrict__ out) {
    int g = threadIdx.x;
    if (g < N_GRAPHS) {
        float cnt = fmaxf(pcnt[g], 1.0f);
        float s = 0.f;
        for (int c = 0; c < 64; ++c) s += pooled[g * 64 + c] * Wout[c];
        out[g] = s / cnt + bout[0];
    }
}

// ---------------------------------------------------------------------------
extern "C" void kernel_launch(void* const* d_in, const int* in_sizes, int n_in,
                              void* d_out, int out_size, void* d_ws, size_t ws_size,
                              hipStream_t stream) {
    const float* x    = (const float*)d_in[0];
    const int*   ei   = (const int*)d_in[1];
    const float* ew   = (const float*)d_in[2];
    const int*   batch= (const int*)d_in[3];
    const float* W1   = (const float*)d_in[4];
    const float* b1   = (const float*)d_in[5];
    const float* W2   = (const float*)d_in[6];
    const float* b2   = (const float*)d_in[7];
    const float* g1   = (const float*)d_in[8];
    const float* be1  = (const float*)d_in[9];
    const float* g2   = (const float*)d_in[10];
    const float* be2  = (const float*)d_in[11];
    const float* Wout = (const float*)d_in[12];
    const float* bout = (const float*)d_in[13];
    float* out = (float*)d_out;

    char* w = (char*)d_ws;
    size_t o = 0;
    auto alloc = [&](size_t bytes) -> void* {
        void* p = w + o;
        o = (o + bytes + 255) & ~(size_t)255;
        return p;
    };
    int*   cnt2    = (int*)alloc(NCNT * 4);
    int*   soff    = (int*)alloc((NCNT + 1) * 4);
    int*   cur     = (int*)alloc(NCNT * 4);
    float* dinv    = (float*)alloc(N_NODES * 4);
    float* bnshard = (float*)alloc(NSHARD * 128 * 4);
    float* scale1  = (float*)alloc(64 * 4);
    float* shift1  = (float*)alloc(64 * 4);
    float* scale2  = (float*)alloc(64 * 4);
    float* shift2  = (float*)alloc(64 * 4);
    float* pooled  = (float*)alloc(N_GRAPHS * 64 * 4);
    float* pcnt    = (float*)alloc(N_GRAPHS * 4);
    uint2* ebuf    = (uint2*)alloc((size_t)N_EDGES * 8);
    float* bufA    = (float*)alloc((size_t)N_NODES * 64 * 4);
    float* bufB    = (float*)alloc((size_t)N_NODES * 64 * 4);
    if (o > ws_size) return;

    hipMemsetAsync(cnt2, 0, NCNT * 4, stream);
    hipMemsetAsync(bnshard, 0, NSHARD * 128 * 4, stream);
    hipMemsetAsync(pooled, 0, N_GRAPHS * 64 * 4, stream);
    hipMemsetAsync(pcnt, 0, N_GRAPHS * 4, stream);

    k_count<<<BIN_GRID, 256, 0, stream>>>(ei, cnt2);
    k_scan6k<<<1, 256, 0, stream>>>(cnt2, soff, cur);
    k_bin<<<BIN_GRID, 256, 0, stream>>>(ei, ew, cur, ebuf);
    k_degb<<<NBUCK, 256, 0, stream>>>(ebuf, soff, dinv);
    k_norm<<<NBUCK, 256, 0, stream>>>(ebuf, soff, dinv);

    // layer 1
    k_gemm<128, false><<<(N_NODES + 127) / 128, 256, 0, stream>>>(x, W1, nullptr, nullptr, bufA);
    k_agg<<<NBUCK, 512, 0, stream>>>(bufA, ebuf, soff, dinv, b1, bufB, bnshard);
    k_bn_final<<<1, 256, 0, stream>>>(bnshard, g1, be1, scale1, shift1);

    // layer 2
    k_gemm<64, true><<<(N_NODES + 127) / 128, 256, 0, stream>>>(bufB, W2, scale1, shift1, bufA);
    k_agg<<<NBUCK, 512, 0, stream>>>(bufA, ebuf, soff, dinv, b2, bufB, bnshard);
    k_bn_final<<<1, 256, 0, stream>>>(bnshard, g2, be2, scale2, shift2);

    // pool + output
    k_pool<<<(N_NODES + 1023) / 1024, 256, 0, stream>>>(bufB, scale2, shift2, batch, pooled, pcnt);
    k_out<<<1, 64, 0, stream>>>(pooled, pcnt, Wout, bout, out);
}

// Round 3
// 848.721 us; speedup vs baseline: 4.0578x; 4.0578x over previous
//
#include <hip/hip_runtime.h>
#include <stdint.h>

#define N_NODES 100000
#define N_EDGES 3200000
#define IN_DIM 128
#define HID 64
#define N_GRAPHS 64
#define BN_EPS 1e-5f
#define NSHARD 16
#define BUCK_SH 7
#define BUCK_SZ 128
#define NBUCK ((N_NODES + BUCK_SZ - 1) / BUCK_SZ)   // 782
#define NCNT (NBUCK * 8)                             // 6256
#define BIN_GRID 2048

// ---------------------------------------------------------------------------
// count edges per (bucket, sub-stream). For 256-thread blocks with this grid
// stride, s=(e>>8)&7 == blockIdx&7 == XCD id -> counters are XCD-L2-local.
__global__ void k_count(const int* __restrict__ ei, int* __restrict__ cnt2) {
    int stride = gridDim.x * blockDim.x;
    for (int e = blockIdx.x * blockDim.x + threadIdx.x; e < N_EDGES; e += stride) {
        int c = ei[N_EDGES + e];
        int s = (e >> 8) & 7;
        atomicAdd(&cnt2[((c >> BUCK_SH) << 3) + s], 1);
    }
}

// single-block exclusive scan of cnt2[6256] -> soff[6257]; init cursors; nptr tail
__global__ void k_scan6k(const int* __restrict__ cnt2, int* __restrict__ soff,
                         int* __restrict__ cur, int* __restrict__ nptr) {
    __shared__ int parts[256];
    int t = threadIdx.x;
    int s = 0;
    for (int i = 0; i < 25; ++i) {
        int idx = t * 25 + i;
        if (idx < NCNT) s += cnt2[idx];
    }
    parts[t] = s;
    __syncthreads();
    for (int off = 1; off < 256; off <<= 1) {
        int x = (t >= off) ? parts[t - off] : 0;
        __syncthreads();
        parts[t] += x;
        __syncthreads();
    }
    int run = (t > 0) ? parts[t - 1] : 0;
    for (int i = 0; i < 25; ++i) {
        int idx = t * 25 + i;
        if (idx < NCNT) {
            soff[idx] = run;
            cur[idx] = run;
            run += cnt2[idx];
        }
    }
    if (t == 255) soff[NCNT] = parts[255];
    if (t == 0) nptr[N_NODES] = N_EDGES;
}

// bin edges into bucket-substream regions: ebuf[p] = {r | (c_local<<17), w}
__global__ void k_bin(const int* __restrict__ ei, const float* __restrict__ ew,
                      int* __restrict__ cur, uint2* __restrict__ ebuf) {
    int stride = gridDim.x * blockDim.x;
    for (int e = blockIdx.x * blockDim.x + threadIdx.x; e < N_EDGES; e += stride) {
        int r = ei[e];
        int c = ei[N_EDGES + e];
        float w = ew[e];
        int s = (e >> 8) & 7;
        int p = atomicAdd(&cur[((c >> BUCK_SH) << 3) + s], 1);
        ebuf[p] = make_uint2((unsigned)(r | ((c & (BUCK_SZ - 1)) << 17)),
                             __float_as_uint(w));
    }
}

// per-bucket weighted degree -> dinv (all edges with col c live in c's bucket)
__global__ __launch_bounds__(256) void k_degb(const uint2* __restrict__ ebuf,
                                              const int* __restrict__ soff,
                                              float* __restrict__ dinv) {
    __shared__ float dacc[BUCK_SZ];
    int b = blockIdx.x, t = threadIdx.x;
    if (t < BUCK_SZ) dacc[t] = 0.f;
    __syncthreads();
    int beg = soff[b << 3], end = soff[(b << 3) + 8];
    for (int i = beg + t; i < end; i += 256) {
        uint2 u = ebuf[i];
        atomicAdd(&dacc[u.x >> 17], __uint_as_float(u.y));
    }
    __syncthreads();
    int node = b * BUCK_SZ + t;
    if (t < BUCK_SZ && node < N_NODES) dinv[node] = rsqrtf(dacc[t] + 1.0f);
}

// per-bucket counting sort by local dest + fused norm computation.
// ebuf (bucket-grouped) -> ebuf2 (fully per-node grouped CSR), nptr = row starts
__global__ __launch_bounds__(256) void k_sortnorm(const uint2* __restrict__ ebuf,
                                                  const int* __restrict__ soff,
                                                  const float* __restrict__ dinv,
                                                  uint2* __restrict__ ebuf2,
                                                  int* __restrict__ nptr) {
    __shared__ int scnt[BUCK_SZ];
    __shared__ int scur[BUCK_SZ];
    __shared__ float sdi[BUCK_SZ];
    int b = blockIdx.x, t = threadIdx.x;
    if (t < BUCK_SZ) {
        scnt[t] = 0;
        int node = b * BUCK_SZ + t;
        sdi[t] = (node < N_NODES) ? dinv[node] : 0.f;
    }
    __syncthreads();
    int beg = soff[b << 3], end = soff[(b << 3) + 8];
    // pass 1: histogram of local dest
    for (int i = beg + t; i < end; i += 256)
        atomicAdd(&scnt[ebuf[i].x >> 17], 1);
    __syncthreads();
    // inclusive scan over 128 entries (all 256 threads hit the barriers)
    for (int off = 1; off < BUCK_SZ; off <<= 1) {
        int x = 0;
        if (t < BUCK_SZ && t >= off) x = scnt[t - off];
        __syncthreads();
        if (t < BUCK_SZ) scnt[t] += x;
        __syncthreads();
    }
    if (t < BUCK_SZ) {
        int excl = (t > 0) ? scnt[t - 1] : 0;
        scur[t] = beg + excl;
        int node = b * BUCK_SZ + t;
        if (node < N_NODES) nptr[node] = beg + excl;
    }
    __syncthreads();
    // pass 2: scatter within bucket (32 KB window, L2-resident) + norm
    for (int i = beg + t; i < end; i += 256) {
        uint2 u = ebuf[i];
        int r = u.x & 131071;
        int cl = u.x >> 17;
        float nm = dinv[r] * __uint_as_float(u.y) * sdi[cl];
        int p = atomicAdd(&scur[cl], 1);
        ebuf2[p] = make_uint2((unsigned)r, __float_as_uint(nm));
    }
}

// ---------------------------------------------------------------------------
// GEMM: out[n][c] = sum_k in[n][k] * W[k][c], optional fused BN+ReLU on input
template <int K, bool BN>
__global__ __launch_bounds__(256) void k_gemm(const float* __restrict__ in,
                                              const float* __restrict__ W,
                                              const float* __restrict__ scale,
                                              const float* __restrict__ shift,
                                              float* __restrict__ out) {
    __shared__ float ws[K * 64];
    __shared__ float xs[32 * 132];
    __shared__ float ssc[64], ssh[64];
    int t = threadIdx.x;
    int nbase = blockIdx.x * 128;

#pragma unroll
    for (int i = 0; i < K / 16; ++i) {
        int idx = t + 256 * i;
        ((float4*)ws)[idx] = ((const float4*)W)[idx];
    }
    if (BN && t < 64) { ssc[t] = scale[t]; ssh[t] = shift[t]; }

    int cg = t & 15;
    int ng = t >> 4;
    float acc[8][4];
#pragma unroll
    for (int i = 0; i < 8; ++i)
#pragma unroll
        for (int j = 0; j < 4; ++j) acc[i][j] = 0.f;

    for (int k0 = 0; k0 < K; k0 += 32) {
        __syncthreads();
#pragma unroll
        for (int i = 0; i < 4; ++i) {
            int idx = t + 256 * i;
            int row = idx >> 3;
            int kq = idx & 7;
            int node = nbase + row;
            float4 v = make_float4(0.f, 0.f, 0.f, 0.f);
            if (node < N_NODES)
                v = *(const float4*)(in + (size_t)node * K + k0 + kq * 4);
            float vv[4] = {v.x, v.y, v.z, v.w};
#pragma unroll
            for (int u = 0; u < 4; ++u) {
                float val = vv[u];
                if (BN) {
                    int k = k0 + kq * 4 + u;
                    val = fmaxf(ssc[k] * val + ssh[k], 0.f);
                }
                xs[(kq * 4 + u) * 132 + row] = val;
            }
        }
        __syncthreads();
#pragma unroll
        for (int k = 0; k < 32; ++k) {
            float4 wv = *(const float4*)(ws + (k0 + k) * 64 + cg * 4);
            float4 xa = *(const float4*)(xs + k * 132 + ng * 8);
            float4 xb = *(const float4*)(xs + k * 132 + ng * 8 + 4);
            float xv[8] = {xa.x, xa.y, xa.z, xa.w, xb.x, xb.y, xb.z, xb.w};
            float wvv[4] = {wv.x, wv.y, wv.z, wv.w};
#pragma unroll
            for (int i = 0; i < 8; ++i)
#pragma unroll
                for (int j = 0; j < 4; ++j) acc[i][j] += xv[i] * wvv[j];
        }
    }
#pragma unroll
    for (int i = 0; i < 8; ++i) {
        int node = nbase + ng * 8 + i;
        if (node < N_NODES) {
            float4 o4 = make_float4(acc[i][0], acc[i][1], acc[i][2], acc[i][3]);
            *(float4*)(out + (size_t)node * 64 + cg * 4) = o4;
        }
    }
}

// ---------------------------------------------------------------------------
// CSR gather-aggregation: wave per node (lane=channel), register accumulation,
// explicit 8-deep load pipelining for MLP. Fused self-loop, bias, BN partials.
__global__ __launch_bounds__(256) void k_agg(const float* __restrict__ hin,
                                             const uint2* __restrict__ ebuf2,
                                             const int* __restrict__ nptr,
                                             const float* __restrict__ dinv,
                                             const float* __restrict__ bias,
                                             float* __restrict__ hout,
                                             float* __restrict__ bn_shard) {
    int wave = threadIdx.x >> 6;
    int lane = threadIdx.x & 63;
    float s = 0.f, q = 0.f;
    float bl = bias[lane];
    int vbase = blockIdx.x * 32 + wave * 8;
    for (int vi = 0; vi < 8; ++vi) {
        int v = vbase + vi;
        if (v >= N_NODES) break;
        int beg = nptr[v], end = nptr[v + 1];
        float acc = 0.f;
        int j = beg;
        for (; j + 8 <= end; j += 8) {
            float fv[8], fn[8];
#pragma unroll
            for (int u = 0; u < 8; ++u) {
                uint2 e = ebuf2[j + u];
                fn[u] = __uint_as_float(e.y);
                fv[u] = hin[((size_t)e.x << 6) + lane];
            }
#pragma unroll
            for (int u = 0; u < 8; ++u) acc = fmaf(fn[u], fv[u], acc);
        }
        for (; j < end; ++j) {
            uint2 e = ebuf2[j];
            acc = fmaf(__uint_as_float(e.y), hin[((size_t)e.x << 6) + lane], acc);
        }
        float dv = dinv[v];
        acc = fmaf(dv * dv, hin[((size_t)v << 6) + lane], acc);
        acc += bl;
        hout[((size_t)v << 6) + lane] = acc;
        s += acc;
        q += acc * acc;
    }
    __shared__ float sm[4][64], qm[4][64];
    sm[wave][lane] = s;
    qm[wave][lane] = q;
    __syncthreads();
    if (wave == 0) {
        float ts = sm[0][lane] + sm[1][lane] + sm[2][lane] + sm[3][lane];
        float tq = qm[0][lane] + qm[1][lane] + qm[2][lane] + qm[3][lane];
        float* shard = bn_shard + (blockIdx.x & (NSHARD - 1)) * 128;
        atomicAdd(&shard[lane], ts);
        atomicAdd(&shard[64 + lane], tq);
    }
}

// reduce BN shards -> scale/shift; re-zero shards for the next layer
__global__ void k_bn_final(float* __restrict__ bn_shard, const float* __restrict__ gamma,
                           const float* __restrict__ beta, float* __restrict__ scale,
                           float* __restrict__ shift) {
    int t = threadIdx.x;
    if (t < 64) {
        float s = 0.f, q = 0.f;
        for (int i = 0; i < NSHARD; ++i) {
            s += bn_shard[i * 128 + t];
            q += bn_shard[i * 128 + 64 + t];
        }
        float mean = s * (1.0f / N_NODES);
        float var = q * (1.0f / N_NODES) - mean * mean;
        float sc = gamma[t] * rsqrtf(var + BN_EPS);
        scale[t] = sc;
        shift[t] = beta[t] - mean * sc;
    }
    __syncthreads();
    for (int i = t; i < NSHARD * 128; i += 256) bn_shard[i] = 0.f;
}

// ---------------------------------------------------------------------------
__global__ __launch_bounds__(256) void k_pool(const float* __restrict__ a2,
                                              const float* __restrict__ scale,
                                              const float* __restrict__ shift,
                                              const int* __restrict__ batch,
                                              float* __restrict__ pooled,
                                              float* __restrict__ pcnt) {
    int t = threadIdx.x;
    int c = t & 63;
    int rg = t >> 6;
    int base = blockIdx.x * 1024;
    float sc = scale[c], sh = shift[c];
    int gcur = -1;
    float acc = 0.f, cacc = 0.f;
    for (int i = rg; i < 1024; i += 4) {
        int v = base + i;
        if (v >= N_NODES) break;
        int g = batch[v];
        if (g != gcur) {
            if (gcur >= 0) {
                atomicAdd(&pooled[gcur * 64 + c], acc);
                if (c == 0) atomicAdd(&pcnt[gcur], cacc);
            }
            gcur = g;
            acc = 0.f;
            cacc = 0.f;
        }
        float h = fmaxf(sc * a2[(size_t)v * 64 + c] + sh, 0.f);
        acc += h;
        cacc += 1.f;
    }
    if (gcur >= 0) {
        atomicAdd(&pooled[gcur * 64 + c], acc);
        if (c == 0) atomicAdd(&pcnt[gcur], cacc);
    }
}

__global__ void k_out(const float* __restrict__ pooled, const float* __restrict__ pcnt,
                      const float* __restrict__ Wout, const float* __restrict__ bout,
                      float* __restrict__ out) {
    int g = threadIdx.x;
    if (g < N_GRAPHS) {
        float cnt = fmaxf(pcnt[g], 1.0f);
        float s = 0.f;
        for (int c = 0; c < 64; ++c) s += pooled[g * 64 + c] * Wout[c];
        out[g] = s / cnt + bout[0];
    }
}

// ---------------------------------------------------------------------------
extern "C" void kernel_launch(void* const* d_in, const int* in_sizes, int n_in,
                              void* d_out, int out_size, void* d_ws, size_t ws_size,
                              hipStream_t stream) {
    const float* x    = (const float*)d_in[0];
    const int*   ei   = (const int*)d_in[1];
    const float* ew   = (const float*)d_in[2];
    const int*   batch= (const int*)d_in[3];
    const float* W1   = (const float*)d_in[4];
    const float* b1   = (const float*)d_in[5];
    const float* W2   = (const float*)d_in[6];
    const float* b2   = (const float*)d_in[7];
    const float* g1   = (const float*)d_in[8];
    const float* be1  = (const float*)d_in[9];
    const float* g2   = (const float*)d_in[10];
    const float* be2  = (const float*)d_in[11];
    const float* Wout = (const float*)d_in[12];
    const float* bout = (const float*)d_in[13];
    float* out = (float*)d_out;

    char* w = (char*)d_ws;
    size_t o = 0;
    auto alloc = [&](size_t bytes) -> void* {
        void* p = w + o;
        o = (o + bytes + 255) & ~(size_t)255;
        return p;
    };
    int*   cnt2    = (int*)alloc(NCNT * 4);
    int*   soff    = (int*)alloc((NCNT + 1) * 4);
    int*   cur     = (int*)alloc(NCNT * 4);
    int*   nptr    = (int*)alloc((N_NODES + 1) * 4);
    float* dinv    = (float*)alloc(N_NODES * 4);
    float* bnshard = (float*)alloc(NSHARD * 128 * 4);
    float* scale1  = (float*)alloc(64 * 4);
    float* shift1  = (float*)alloc(64 * 4);
    float* scale2  = (float*)alloc(64 * 4);
    float* shift2  = (float*)alloc(64 * 4);
    float* pooled  = (float*)alloc(N_GRAPHS * 64 * 4);
    float* pcnt    = (float*)alloc(N_GRAPHS * 4);
    uint2* ebuf2   = (uint2*)alloc((size_t)N_EDGES * 8);
    float* bufA    = (float*)alloc((size_t)N_NODES * 64 * 4);
    float* bufB    = (float*)alloc((size_t)N_NODES * 64 * 4);
    // ebuf (unsorted, bucket-grouped) is dead before GEMM1 writes bufA: alias them.
    uint2* ebuf    = (uint2*)bufA;
    if (o > ws_size) return;

    hipMemsetAsync(cnt2, 0, NCNT * 4, stream);
    hipMemsetAsync(bnshard, 0, NSHARD * 128 * 4, stream);
    hipMemsetAsync(pooled, 0, N_GRAPHS * 64 * 4, stream);
    hipMemsetAsync(pcnt, 0, N_GRAPHS * 4, stream);

    k_count<<<BIN_GRID, 256, 0, stream>>>(ei, cnt2);
    k_scan6k<<<1, 256, 0, stream>>>(cnt2, soff, cur, nptr);
    k_bin<<<BIN_GRID, 256, 0, stream>>>(ei, ew, cur, ebuf);
    k_degb<<<NBUCK, 256, 0, stream>>>(ebuf, soff, dinv);
    k_sortnorm<<<NBUCK, 256, 0, stream>>>(ebuf, soff, dinv, ebuf2, nptr);

    // layer 1
    k_gemm<128, false><<<(N_NODES + 127) / 128, 256, 0, stream>>>(x, W1, nullptr, nullptr, bufA);
    k_agg<<<(N_NODES + 31) / 32, 256, 0, stream>>>(bufA, ebuf2, nptr, dinv, b1, bufB, bnshard);
    k_bn_final<<<1, 256, 0, stream>>>(bnshard, g1, be1, scale1, shift1);

    // layer 2
    k_gemm<64, true><<<(N_NODES + 127) / 128, 256, 0, stream>>>(bufB, W2, scale1, shift1, bufA);
    k_agg<<<(N_NODES + 31) / 32, 256, 0, stream>>>(bufA, ebuf2, nptr, dinv, b2, bufB, bnshard);
    k_bn_final<<<1, 256, 0, stream>>>(bnshard, g2, be2, scale2, shift2);

    // pool + output
    k_pool<<<(N_NODES + 1023) / 1024, 256, 0, stream>>>(bufB, scale2, shift2, batch, pooled, pcnt);
    k_out<<<1, 64, 0, stream>>>(pooled, pcnt, Wout, bout, out);
}